// Round 6
// baseline (125.309 us; speedup 1.0000x reference)
//
#include <hip/hip_runtime.h>
#include <hip/hip_bf16.h>
#include <stdint.h>

// ---------------------------------------------------------------------------
// SupervisedContrastiveLoss, B=4096, D=1024, C=32, T=0.1, eps=1e-8
// out = (1/B) * [ sum_i (log(denom_i)*W_i - posS_i) - pw*INV_T*||G||_F^2 ]
// R6: BARRIER-FREE gemm. One wave (64 thr) per 64x64 tile, wave-private LDS
//     staging (16 KB dbuf), software pipeline via global_load_lds + inline-asm
//     s_waitcnt vmcnt(8) (never 0). 2080 upper-tri tiles + 1024 G units in one
//     dispatch. W folded into finalize. No __syncthreads anywhere in scl_main.
// ---------------------------------------------------------------------------

typedef float f32x4 __attribute__((ext_vector_type(4)));
typedef float f32x2 __attribute__((ext_vector_type(2)));
typedef long i64;

#define INV_T 10.0f
#define Z_SCALE (INV_T / 256.0f)   // both fp8 operands carry x16

#define GLD16(gp, lp)                                                          \
    __builtin_amdgcn_global_load_lds(                                          \
        (const __attribute__((address_space(1))) uint32_t*)(gp),               \
        (__attribute__((address_space(3))) uint32_t*)(lp), 16, 0, 0)

// workspace layout (bytes)
#define OFF_RNF8  0                         // 4096*1024 = 4194304
#define OFF_DENOM 4194304                   // 4096*4
#define OFF_POSS  (OFF_DENOM + 16384)
#define OFF_G     (OFF_POSS + 16384)        // 1024*32*4 = 131072
#define OFF_OACC  (OFF_G + 131072)          // double
#define OFF_DONE  (OFF_OACC + 16)           // int
#define ZERO_SPAN 167936                    // 41*4096 >= 163904 (zeroed region)
#define OFF_CSP   (OFF_DENOM + ZERO_SPAN)   // 32*32*4 colsum partials
#define OFF_CCP   (OFF_CSP + 4096)          // 32*32*4 histogram partials

// ---------------- D1: normalize -> fp8(x16) | prep partials | zero ----------
__global__ __launch_bounds__(256) void scl_stage1(const float* __restrict__ rep,
                                                  const float* __restrict__ sl,
                                                  const int* __restrict__ labels,
                                                  uint32_t* __restrict__ rnf8,
                                                  float* __restrict__ cs_part,
                                                  int* __restrict__ cc_part,
                                                  char* __restrict__ zbase) {
    int b = blockIdx.x;
    int t = threadIdx.x;
    if (b < 4096) {
        int row = b;
        const float4* src = reinterpret_cast<const float4*>(rep + (size_t)row * 1024);
        float4 v = src[t];
        float s = v.x * v.x + v.y * v.y + v.z * v.z + v.w * v.w;
#pragma unroll
        for (int m = 1; m < 64; m <<= 1) s += __shfl_xor(s, m, 64);
        __shared__ float red[4];
        if ((t & 63) == 0) red[t >> 6] = s;
        __syncthreads();
        s = red[0] + red[1] + red[2] + red[3];
        float nf = 16.0f / fmaxf(sqrtf(s), 1e-8f);   // x16 into fp8 normal range
        int p = 0;
        p = __builtin_amdgcn_cvt_pk_fp8_f32(v.x * nf, v.y * nf, p, false);
        p = __builtin_amdgcn_cvt_pk_fp8_f32(v.z * nf, v.w * nf, p, true);
        rnf8[row * 256 + t] = (uint32_t)p;
    } else if (b < 4128) {
        // prep partials: colsum of soft_labels + class histogram (128 rows/slab)
        __shared__ float part[8][32];
        __shared__ int bins[32];
        int bb = b - 4096;
        if (t < 32) bins[t] = 0;
        __syncthreads();
        if (t < 128) atomicAdd(&bins[labels[bb * 128 + t]], 1);
        int c = t & 31, rg = t >> 5;
        float s = 0.f;
#pragma unroll 4
        for (int k = 0; k < 16; ++k) {
            int i = bb * 128 + rg * 16 + k;
            s += sl[i * 32 + c];
        }
        part[rg][c] = s;
        __syncthreads();
        if (t < 32) {
            float tot = 0.f;
#pragma unroll
            for (int g = 0; g < 8; ++g) tot += part[g][t];
            cs_part[bb * 32 + t] = tot;
            cc_part[bb * 32 + t] = bins[t];
        }
    } else {
        // zero blocks: denom/posS/G/oacc/done
        int zb = b - 4128;
        *(uint4*)(zbase + (size_t)zb * 4096 + t * 16) = (uint4){0, 0, 0, 0};
    }
}

// ---------------- D2: barrier-free gemm (1 wave/tile) + G units -------------
// blocks [0,2080): upper-tri 64x64 tiles over the 64-grid.
// blocks [2080,3104): G = rn^T @ SL, 1024 units (32 dblk x 32 ks).
__global__ __launch_bounds__(64) void scl_main(const uint8_t* __restrict__ rnf8,
                                               const float* __restrict__ sl,
                                               const int* __restrict__ labels,
                                               float* __restrict__ denom,
                                               float* __restrict__ posS,
                                               float* __restrict__ G) {
    int lane = threadIdx.x;

    if (blockIdx.x >= 2080) {
        // ---- G unit: 32 d x 128 rows ----
        int u = blockIdx.x - 2080;
        int dblk = u & 31, ks = u >> 5;
        int c = lane & 31, dq = lane >> 5;      // dq in {0,1}, 16 d each
        int d0 = dblk * 32 + dq * 16;
        f32x2 acc2[8];
#pragma unroll
        for (int j = 0; j < 8; ++j) acc2[j] = (f32x2){0.f, 0.f};
        int i0 = ks * 128;
#pragma unroll 2
        for (int k = 0; k < 128; ++k) {
            int i = i0 + k;
            uint4 rv = *(const uint4*)&rnf8[(size_t)i * 1024 + d0];
            float sv = sl[i * 32 + c];
            f32x2 sv2 = {sv, sv};
            acc2[0] += __builtin_amdgcn_cvt_pk_f32_fp8((int)rv.x, false) * sv2;
            acc2[1] += __builtin_amdgcn_cvt_pk_f32_fp8((int)rv.x, true) * sv2;
            acc2[2] += __builtin_amdgcn_cvt_pk_f32_fp8((int)rv.y, false) * sv2;
            acc2[3] += __builtin_amdgcn_cvt_pk_f32_fp8((int)rv.y, true) * sv2;
            acc2[4] += __builtin_amdgcn_cvt_pk_f32_fp8((int)rv.z, false) * sv2;
            acc2[5] += __builtin_amdgcn_cvt_pk_f32_fp8((int)rv.z, true) * sv2;
            acc2[6] += __builtin_amdgcn_cvt_pk_f32_fp8((int)rv.w, false) * sv2;
            acc2[7] += __builtin_amdgcn_cvt_pk_f32_fp8((int)rv.w, true) * sv2;
        }
#pragma unroll
        for (int j = 0; j < 8; ++j) {
            atomicAdd(&G[(d0 + 2 * j) * 32 + c], acc2[j][0] * 0.0625f);
            atomicAdd(&G[(d0 + 2 * j + 1) * 32 + c], acc2[j][1] * 0.0625f);
        }
        return;
    }

    // ---- gemm tile: one wave, 64x64 output, wave-private LDS ----
    __shared__ __align__(16) uint8_t Ls[16384];  // dbuf: {A 4K, B 4K} x 2

    int L = blockIdx.x;
    int bi = 0, rem = L;
    while (rem >= 64 - bi) { rem -= 64 - bi; ++bi; }
    int bj = bi + rem;
    int rowA0 = bi * 64, colB0 = bj * 64;

    int m_ = lane & 15, g = lane >> 4;
    int r4 = lane >> 2;                       // staged row 0..15 (per GLD16)
    int csw = (lane & 3) ^ ((lane >> 3) & 3); // global 16B-chunk to fetch
    const uint8_t* gA = rnf8 + (size_t)(rowA0 + r4) * 1024 + csw * 16;
    const uint8_t* gB = rnf8 + (size_t)(colB0 + r4) * 1024 + csw * 16;
    uint8_t* As = Ls;
    uint8_t* Bs = Ls + 4096;

#define ISSUE8(KT, NB)                                                         \
    {                                                                          \
        const uint8_t* pa = gA + (KT) * 64;                                    \
        const uint8_t* pb = gB + (KT) * 64;                                    \
        GLD16(pa,          As + (NB));                                         \
        GLD16(pa + 16384,  As + (NB) + 1024);                                  \
        GLD16(pa + 32768,  As + (NB) + 2048);                                  \
        GLD16(pa + 49152,  As + (NB) + 3072);                                  \
        GLD16(pb,          Bs + (NB));                                         \
        GLD16(pb + 16384,  Bs + (NB) + 1024);                                  \
        GLD16(pb + 32768,  Bs + (NB) + 2048);                                  \
        GLD16(pb + 49152,  Bs + (NB) + 3072);                                  \
    }

    f32x4 acc[4][4];
#pragma unroll
    for (int a = 0; a < 4; ++a)
#pragma unroll
        for (int b = 0; b < 4; ++b) acc[a][b] = (f32x4){0.f, 0.f, 0.f, 0.f};

    // frag LDS 16B-slot: global chunk q of row r lives at slot q^((r>>1)&3)
    int fsw = (g ^ ((m_ >> 1) & 3)) * 16;

    ISSUE8(0, 0);                                  // prologue: kt0 -> buf0
#pragma unroll
    for (int kt = 0; kt < 16; ++kt) {
        int cb = (kt & 1) * 8192;
        if (kt < 15) {
            ISSUE8(kt + 1, 8192 - cb);             // prefetch kt+1 -> other buf
            asm volatile("s_waitcnt vmcnt(8)" ::: "memory");  // kt's 8 done
        } else {
            asm volatile("s_waitcnt vmcnt(0)" ::: "memory");
        }
        f32x4 aq[4], bq[4];
#pragma unroll
        for (int ti = 0; ti < 4; ++ti)
            aq[ti] = *(const f32x4*)&As[cb + (ti * 16 + m_) * 64 + fsw];
#pragma unroll
        for (int tj = 0; tj < 4; ++tj)
            bq[tj] = *(const f32x4*)&Bs[cb + (tj * 16 + m_) * 64 + fsw];
#pragma unroll
        for (int s = 0; s < 2; ++s)
#pragma unroll
            for (int ti = 0; ti < 4; ++ti)
#pragma unroll
                for (int tj = 0; tj < 4; ++tj) {
                    i64 a = ((const i64*)&aq[ti])[s];
                    i64 b = ((const i64*)&bq[tj])[s];
                    acc[ti][tj] = __builtin_amdgcn_mfma_f32_16x16x32_fp8_fp8(
                        a, b, acc[ti][tj], 0, 0, 0);
                }
    }
#undef ISSUE8

    // epilogue: C layout col=lane&15, row=(lane>>4)*4+reg
    bool isDiag = (bi == bj);
    int cl = m_;
    float colE[4] = {0.f, 0.f, 0.f, 0.f}, colP[4] = {0.f, 0.f, 0.f, 0.f};
    int lcj[4];
#pragma unroll
    for (int tj = 0; tj < 4; ++tj) lcj[tj] = labels[colB0 + tj * 16 + cl];
#pragma unroll
    for (int ti = 0; ti < 4; ++ti) {
        int rowLoc = ti * 16 + g * 4;
        float rE[4] = {0.f, 0.f, 0.f, 0.f}, rP[4] = {0.f, 0.f, 0.f, 0.f};
        int lr[4];
#pragma unroll
        for (int r = 0; r < 4; ++r) lr[r] = labels[rowA0 + rowLoc + r];
#pragma unroll
        for (int tj = 0; tj < 4; ++tj) {
            int gCol = colB0 + tj * 16 + cl;
            int lc = lcj[tj];
            f32x4 a = acc[ti][tj];
#pragma unroll
            for (int r = 0; r < 4; ++r) {
                int gRow = rowA0 + rowLoc + r;
                float z = Z_SCALE * a[r];
                float e = __expf(z);
                bool offd = (gRow != gCol);
                if (!offd) e = 0.f;
                rE[r] += e;
                colE[tj] += e;
                if (offd && (lr[r] == lc)) { rP[r] += z; colP[tj] += z; }
            }
        }
#pragma unroll
        for (int r = 0; r < 4; ++r) {
            float v = rE[r], p = rP[r];
#pragma unroll
            for (int msk = 1; msk < 16; msk <<= 1) {
                v += __shfl_xor(v, msk, 64);
                p += __shfl_xor(p, msk, 64);
            }
            if (cl == 0) {
                int gRow = rowA0 + rowLoc + r;
                atomicAdd(&denom[gRow], v);
                atomicAdd(&posS[gRow], p);
            }
        }
    }
    if (!isDiag) {
#pragma unroll
        for (int tj = 0; tj < 4; ++tj) {
            float v = colE[tj], p = colP[tj];
            v += __shfl_xor(v, 16, 64); p += __shfl_xor(p, 16, 64);
            v += __shfl_xor(v, 32, 64); p += __shfl_xor(p, 32, 64);
            if (g == 0) {
                int gCol = colB0 + tj * 16 + cl;
                atomicAdd(&denom[gCol], v);
                atomicAdd(&posS[gCol], p);
            }
        }
    }
}

// ---------------- D3: finalize (8 row-blocks + 1 G-block), done-counter -----
__global__ __launch_bounds__(256) void scl_finalize(const float* __restrict__ denom,
                                                    const float* __restrict__ posS,
                                                    const float* __restrict__ sl,
                                                    const int* __restrict__ labels,
                                                    const float* __restrict__ cs_part,
                                                    const int* __restrict__ cc_part,
                                                    const float* __restrict__ G,
                                                    const int* __restrict__ pwp,
                                                    double* __restrict__ oacc,
                                                    int* __restrict__ done,
                                                    float* __restrict__ out) {
    int t = threadIdx.x;
    int bits = *pwp;
    float pw = (bits >= -(1 << 22) && bits <= (1 << 22)) ? (float)bits
                                                         : __int_as_float(bits);
    __shared__ double wsum[4];
    double contrib = 0.0;

    if (blockIdx.x < 8) {
        __shared__ __align__(16) float css[32];
        __shared__ int ccs[32];
        if (t < 32) {
            float s = 0.f; int n = 0;
#pragma unroll
            for (int b = 0; b < 32; ++b) {
                s += cs_part[b * 32 + t];
                n += cc_part[b * 32 + t];
            }
            css[t] = s; ccs[t] = n;
        }
        __syncthreads();
        const f32x4* sl4 = (const f32x4*)sl;
        const f32x4* cs4 = (const f32x4*)css;
        double td = 0.0;
#pragma unroll
        for (int h = 0; h < 2; ++h) {
            int i = blockIdx.x * 512 + h * 256 + t;
            float dW = 0.f;
#pragma unroll
            for (int q = 0; q < 8; ++q) {
                f32x4 s = sl4[i * 8 + q];
                f32x4 c = cs4[q];
                dW += s[0] * c[0] + s[1] * c[1] + s[2] * c[2] + s[3] * c[3];
            }
            float Wv = (float)(ccs[labels[i]] - 1) + pw * dW;
            td += (double)(__logf(denom[i]) * Wv - posS[i]);
        }
#pragma unroll
        for (int m = 1; m < 64; m <<= 1) td += __shfl_xor(td, m, 64);
        if ((t & 63) == 0) wsum[t >> 6] = td;
        __syncthreads();
        contrib = wsum[0] + wsum[1] + wsum[2] + wsum[3];
    } else {
        const f32x4* G4 = (const f32x4*)G;
        float gs = 0.f;
#pragma unroll
        for (int q = 0; q < 32; ++q) {
            f32x4 v = G4[q * 256 + t];
            gs += v[0] * v[0] + v[1] * v[1] + v[2] * v[2] + v[3] * v[3];
        }
        double gd = (double)gs;
#pragma unroll
        for (int m = 1; m < 64; m <<= 1) gd += __shfl_xor(gd, m, 64);
        if ((t & 63) == 0) wsum[t >> 6] = gd;
        __syncthreads();
        contrib = -(double)(pw * INV_T) * (wsum[0] + wsum[1] + wsum[2] + wsum[3]);
    }

    if (t == 0) {
        atomicAdd(oacc, contrib);
        __threadfence();
        int old = atomicAdd(done, 1);
        if (old == 8) {  // last of 9 blocks
            double tot = atomicAdd(oacc, 0.0);  // coherent read
            out[0] = (float)(tot * (1.0 / 4096.0));
        }
    }
}

// ---------------------------------------------------------------------------
extern "C" void kernel_launch(void* const* d_in, const int* in_sizes, int n_in,
                              void* d_out, int out_size, void* d_ws, size_t ws_size,
                              hipStream_t stream) {
    const float* rep = (const float*)d_in[0];
    const float* sl = (const float*)d_in[1];
    const int* labels = (const int*)d_in[2];
    const int* pwp = (const int*)d_in[3];

    char* ws = (char*)d_ws;
    uint8_t* rnf8 = (uint8_t*)(ws + OFF_RNF8);
    float* denom = (float*)(ws + OFF_DENOM);
    float* posS = (float*)(ws + OFF_POSS);
    float* G = (float*)(ws + OFF_G);
    double* oacc = (double*)(ws + OFF_OACC);
    int* done = (int*)(ws + OFF_DONE);
    float* cs_part = (float*)(ws + OFF_CSP);
    int* cc_part = (int*)(ws + OFF_CCP);

    scl_stage1<<<4169, 256, 0, stream>>>(rep, sl, labels, (uint32_t*)rnf8,
                                         cs_part, cc_part, ws + OFF_DENOM);
    scl_main<<<3104, 64, 0, stream>>>(rnf8, sl, labels, denom, posS, G);
    scl_finalize<<<9, 256, 0, stream>>>(denom, posS, sl, labels, cs_part, cc_part,
                                        G, pwp, oacc, done, (float*)d_out);
}